// Round 6
// baseline (75784.308 us; speedup 1.0000x reference)
//
#include <hip/hip_runtime.h>
#include <cstdint>
#include <cstddef>

// ---------------------------------------------------------------------------
// LSTM encoder: 5 layers, REVS = (T,F,T,F,T), B=64, T=1024, D=H=384, fp32.
// Per layer: xproj = x(rev)@Wi + b  (parallel GEMM), then sequential scan.
//
// R5/R6 theory: GEMM is LDS-pipe-bound; old Bs read pattern (Bs[k][tx*8])
// was a 4-way bank conflict on half the b128 reads (lanes tx=0,4,8,12 share
// banks); writes (jc=(tid&31)*4) also 4-way. Fix: column split
// {tx*4} u {64+tx*4} for reads, {jb, jb+64} for writes (both 2-way = free).
// Plus BK=16 (24 barriers vs 48) and nontemporal C stores.
// R6 = R5 with the compile fix: __builtin_nontemporal_store needs a clang
// ext_vector_type, not HIP's float4 class.
// Recur: R4 structure (proven 2610us) + NT xp loads / NT xout stores to
// protect the XCD-local L2 holding h_ex.
// ---------------------------------------------------------------------------

#define T_SEQ   1024
#define DD      384
#define HH      384
#define FH      1536
#define NBATCH  64
#define BG      8      // batch rows per group
#define CC      24     // column chunks (64 gate-cols each -> 16 h-cols)
#define JHW     16     // h-columns per wg
#define RTHREADS 512
#define RSMEM_BYTES 31360
// LDS carve: hL 8*388*4 = 12416 | zred 8*64*9*4 = 18432 @12416 | cL 512 @30848

typedef unsigned long long u64;
typedef float fvec4 __attribute__((ext_vector_type(4)));

__device__ __forceinline__ float sigmoidf_(float x) {
  return 1.0f / (1.0f + __expf(-x));
}
__device__ __forceinline__ float tanhf_(float x) {
  float ax = fabsf(x);
  float e  = __expf(-2.0f * ax);
  float r  = (1.0f - e) / (1.0f + e);
  return (x >= 0.0f) ? r : -r;
}

// ---------------------------------------------------------------------------
// xproj GEMM: rows m = trel*64 + b  (M = Tc*64), cols j in [0,1536), K=384.
// 128x128 block, BK=16, 256 threads, 8x8 microtile (cols tx*4 and 64+tx*4).
// Double-buffered LDS, one __syncthreads per BK-step (24 total).
// ---------------------------------------------------------------------------
__global__ __launch_bounds__(256, 3) void gemm_xproj(
    const float* __restrict__ xin, const float* __restrict__ Wi,
    const float* __restrict__ bias, float* __restrict__ xproj,
    int t0, int rev)
{
  __shared__ float As[2][16][132];
  __shared__ float Bs[2][16][132];

  const int tid = threadIdx.x;
  const int tx = tid & 15, ty = tid >> 4;

  // --- bijective XCD decode: all 12 j-blocks of a row-panel on one XCD ---
  const int nyb = gridDim.x / 12;       // number of 128-row panels
  int bx, by;
  if ((nyb & 7) == 0) {
    const int xcd   = blockIdx.x & 7;
    const int s     = blockIdx.x >> 3;
    const int chunk = nyb >> 3;
    by = xcd * chunk + s / 12;
    bx = s % 12;
  } else {
    bx = blockIdx.x % 12;
    by = blockIdx.x / 12;
  }
  const int m0 = by * 128;
  const int j0 = bx * 128;

  // A loader: thread covers row r, k-halves part*8 .. part*8+7
  const int r    = tid >> 1;
  const int part = tid & 1;
  const int m    = m0 + r;
  const int b    = m & 63;
  const int trel = m >> 6;
  const int t    = t0 + trel;
  const int tsrc = rev ? (T_SEQ - 1 - t) : t;
  const float* arow = xin + ((size_t)b * T_SEQ + tsrc) * DD + part * 8;

  // B loader: thread covers k-row kr, cols {jb..jb+3} and {64+jb..64+jb+3}
  const int kr = tid >> 4;              // 0..15
  const int jb = (tid & 15) << 2;       // 0,4,..,60
  const float* brow = Wi + (size_t)kr * FH + j0 + jb;

  float acc[8][8];
#pragma unroll
  for (int i = 0; i < 8; ++i)
#pragma unroll
    for (int j = 0; j < 8; ++j) acc[i][j] = 0.0f;

  // stage kt=0 into buffer 0
  {
    float4 a0 = *(const float4*)(arow);
    float4 a1 = *(const float4*)(arow + 4);
    float4 b0 = *(const float4*)(brow);
    float4 b1 = *(const float4*)(brow + 64);
    As[0][part * 8 + 0][r] = a0.x;
    As[0][part * 8 + 1][r] = a0.y;
    As[0][part * 8 + 2][r] = a0.z;
    As[0][part * 8 + 3][r] = a0.w;
    As[0][part * 8 + 4][r] = a1.x;
    As[0][part * 8 + 5][r] = a1.y;
    As[0][part * 8 + 6][r] = a1.z;
    As[0][part * 8 + 7][r] = a1.w;
    *(float4*)&Bs[0][kr][jb]      = b0;
    *(float4*)&Bs[0][kr][jb + 64] = b1;
  }
  __syncthreads();

  for (int kt = 0; kt < 24; ++kt) {
    const int cur = kt & 1;
    float4 a0n, a1n, b0n, b1n;
    if (kt < 23) {   // issue next-tile loads BEFORE compute (latency hidden)
      a0n = *(const float4*)(arow + (kt + 1) * 16);
      a1n = *(const float4*)(arow + (kt + 1) * 16 + 4);
      b0n = *(const float4*)(brow + (size_t)(kt + 1) * 16 * FH);
      b1n = *(const float4*)(brow + (size_t)(kt + 1) * 16 * FH + 64);
    }
#pragma unroll
    for (int k = 0; k < 16; ++k) {
      float a[8], bb[8];
      *(float4*)&a[0]  = *(const float4*)&As[cur][k][ty * 8];
      *(float4*)&a[4]  = *(const float4*)&As[cur][k][ty * 8 + 4];
      *(float4*)&bb[0] = *(const float4*)&Bs[cur][k][tx * 4];        // 2-way max
      *(float4*)&bb[4] = *(const float4*)&Bs[cur][k][64 + tx * 4];   // 2-way max
#pragma unroll
      for (int i = 0; i < 8; ++i)
#pragma unroll
        for (int j = 0; j < 8; ++j)
          acc[i][j] = fmaf(a[i], bb[j], acc[i][j]);
    }
    if (kt < 23) {
      const int nxt = cur ^ 1;
      As[nxt][part * 8 + 0][r] = a0n.x;
      As[nxt][part * 8 + 1][r] = a0n.y;
      As[nxt][part * 8 + 2][r] = a0n.z;
      As[nxt][part * 8 + 3][r] = a0n.w;
      As[nxt][part * 8 + 4][r] = a1n.x;
      As[nxt][part * 8 + 5][r] = a1n.y;
      As[nxt][part * 8 + 6][r] = a1n.z;
      As[nxt][part * 8 + 7][r] = a1n.w;
      *(float4*)&Bs[nxt][kr][jb]      = b0n;
      *(float4*)&Bs[nxt][kr][jb + 64] = b1n;
      __syncthreads();
    }
  }

  // bias for this thread's 8 columns: {tx*4+jj} and {64+tx*4+jj}
  float bvals[8];
#pragma unroll
  for (int j = 0; j < 4; ++j) {
    bvals[j]     = bias[j0 + tx * 4 + j];
    bvals[j + 4] = bias[j0 + 64 + tx * 4 + j];
  }

#pragma unroll
  for (int i = 0; i < 8; ++i) {
    const int mm = m0 + ty * 8 + i;
    float* orow = xproj + (size_t)mm * FH + j0;
    fvec4 o0, o1;
    o0.x = acc[i][0] + bvals[0]; o0.y = acc[i][1] + bvals[1];
    o0.z = acc[i][2] + bvals[2]; o0.w = acc[i][3] + bvals[3];
    o1.x = acc[i][4] + bvals[4]; o1.y = acc[i][5] + bvals[5];
    o1.z = acc[i][6] + bvals[6]; o1.w = acc[i][7] + bvals[7];
    __builtin_nontemporal_store(o0, (fvec4*)(orow + tx * 4));
    __builtin_nontemporal_store(o1, (fvec4*)(orow + 64 + tx * 4));
  }
}

// ---------------------------------------------------------------------------
// Persistent recurrence kernel. 192 blocks x 512 threads (8 waves), 1/CU.
// XCD-local: bg = blockIdx&7. Wh slice in registers (48/lane).
// Gate columns: gate*384 + cc*16 + jj.
// ---------------------------------------------------------------------------
__global__ __launch_bounds__(RTHREADS) void lstm_recur(
    const float* __restrict__ xp, const float* __restrict__ Wh,
    float* __restrict__ xout, u64* __restrict__ h_ex,
    float* __restrict__ c_state,
    int t0, int Tc, int rev, int layer)
{
  extern __shared__ char smem[];
  float (*hL)[388] = (float (*)[388])(smem);
  float* zred      = (float*)(smem + 12416);
  float* cL        = (float*)(smem + 30848);

  const int wg   = blockIdx.x;
  const int bg   = wg & 7;    // XCD-local: blockIdx%8 -> XCD, whole bg co-XCD
  const int cc   = wg >> 3;
  const int tid  = threadIdx.x;
  const int wave = tid >> 6;
  const int lane = tid & 63;
  const unsigned base = (unsigned)(layer * 1025);  // tag(h_t) = base + t + 1
  const int k0 = wave * 48;

  // --- Wh slice into REGISTERS: lane owns gate-col colg, K-rows k0..k0+47 ---
  const int colg = ((lane >> 4) * HH) + cc * JHW + (lane & 15);
  float wreg[48];
#pragma unroll
  for (int q = 0; q < 48; ++q)
    wreg[q] = Wh[(size_t)(k0 + q) * FH + colg];

  const int rb    = tid >> 4;          // valid for tid<128
  const int rjj   = tid & 15;
  const int bglob = bg * BG + rb;
  const int hb    = cc * JHW + rjj;

  if (tid < 128) {
    cL[tid] = (t0 == 0) ? 0.0f : c_state[(size_t)bglob * HH + hb];
    if (t0 == 0) {
      // publish h_{-1}=0 into slot 1 with tag=base (self-validating)
      u64 pack = ((u64)base << 32);
      __hip_atomic_store(&h_ex[(size_t)(NBATCH * HH) + (size_t)bglob * HH + hb],
                         pack, __ATOMIC_RELAXED, __HIP_MEMORY_SCOPE_AGENT);
    }
  }
  __syncthreads();

  for (int tr = 0; tr < Tc; ++tr) {
    const int t = t0 + tr;

    // prefetch xproj gate values (NT: read-once stream, keep out of L2)
    float xpr0 = 0.f, xpr1 = 0.f, xpr2 = 0.f, xpr3 = 0.f;
    if (tid < 128) {
      const float* xr = xp + ((size_t)tr * NBATCH + bglob) * FH + cc * JHW + rjj;
      xpr0 = __builtin_nontemporal_load(xr);
      xpr1 = __builtin_nontemporal_load(xr + 384);
      xpr2 = __builtin_nontemporal_load(xr + 768);
      xpr3 = __builtin_nontemporal_load(xr + 1152);
    }

    // stage h_{t-1} (this bg's 8x384) from tagged u64 exchange into LDS
    {
      const unsigned tagT = base + (unsigned)t;   // tag of h_{t-1}
      const u64* hsrc = h_ex + (size_t)((t + 1) & 1) * (NBATCH * HH)
                             + (size_t)bg * BG * HH;
      u64 v[6];
#pragma unroll
      for (int k = 0; k < 6; ++k)
        v[k] = __hip_atomic_load(&hsrc[tid + k * RTHREADS],
                                 __ATOMIC_RELAXED, __HIP_MEMORY_SCOPE_AGENT);
#pragma unroll
      for (int k = 0; k < 6; ++k) {
        while ((unsigned)(v[k] >> 32) != tagT) {
          v[k] = __hip_atomic_load(&hsrc[tid + k * RTHREADS],
                                   __ATOMIC_RELAXED, __HIP_MEMORY_SCOPE_AGENT);
        }
        const int e  = tid + k * RTHREADS;
        const int bb = e / HH;
        const int cl = e - bb * HH;
        hL[bb][cl] = __uint_as_float((unsigned)v[k]);
      }
    }
    __syncthreads();   // sync-A: hL staged before FMA

    // K-split partials: wave handles k in [wave*48, wave*48+48), Wh in regs
    float acc[8] = {0, 0, 0, 0, 0, 0, 0, 0};
#pragma unroll
    for (int q4 = 0; q4 < 12; ++q4) {
      const int k = q4 * 4;
#pragma unroll
      for (int bb = 0; bb < 8; ++bb) {
        float4 h4 = *(const float4*)&hL[bb][k0 + k];   // wave-uniform bcast
        acc[bb] = fmaf(wreg[k],     h4.x, acc[bb]);
        acc[bb] = fmaf(wreg[k + 1], h4.y, acc[bb]);
        acc[bb] = fmaf(wreg[k + 2], h4.z, acc[bb]);
        acc[bb] = fmaf(wreg[k + 3], h4.w, acc[bb]);
      }
    }
#pragma unroll
    for (int bb = 0; bb < 8; ++bb)
      zred[(bb * 64 + lane) * 9 + wave] = acc[bb];
    __syncthreads();   // sync-B: zred complete

    // reduce partials, gate math, publish h (tagged atomic, no fence)
    if (tid < 128) {
      float zi = xpr0, zf = xpr1, zg = xpr2, zo = xpr3;
#pragma unroll
      for (int w = 0; w < 8; ++w) {
        zi += zred[(rb * 64 +  0 + rjj) * 9 + w];
        zf += zred[(rb * 64 + 16 + rjj) * 9 + w];
        zg += zred[(rb * 64 + 32 + rjj) * 9 + w];
        zo += zred[(rb * 64 + 48 + rjj) * 9 + w];
      }
      float c = cL[tid];
      c = sigmoidf_(zf) * c + sigmoidf_(zi) * tanhf_(zg);
      float h = sigmoidf_(zo) * tanhf_(c);
      cL[tid] = c;
      u64 pack = ((u64)(base + (unsigned)t + 1u) << 32)
               | (u64)__float_as_uint(h);
      __hip_atomic_store(&h_ex[(size_t)(t & 1) * (NBATCH * HH)
                               + (size_t)bglob * HH + hb],
                         pack, __ATOMIC_RELAXED, __HIP_MEMORY_SCOPE_AGENT);
      const int to = rev ? (T_SEQ - 1 - t) : t;
      __builtin_nontemporal_store(h, &xout[((size_t)bglob * T_SEQ + to) * HH + hb]);
    }
    __syncthreads();   // barrier-3: polls start only after publish
                       // (R1 showed free-running polls saturate local L2)
  }

  // save c for the next chunk launch
  if (tid < 128) {
    c_state[(size_t)bglob * HH + hb] = cL[tid];
  }
}

// ---------------------------------------------------------------------------
extern "C" void kernel_launch(void* const* d_in, const int* in_sizes, int n_in,
                              void* d_out, int out_size, void* d_ws, size_t ws_size,
                              hipStream_t stream) {
  (void)in_sizes; (void)n_in; (void)out_size;

  const float* x  = (const float*)d_in[0];
  const float* Wi = (const float*)d_in[1];
  const float* Wh = (const float*)d_in[2];
  const float* bs = (const float*)d_in[3];
  float* out = (float*)d_out;

  char*  ws      = (char*)d_ws;
  float* c_state = (float*)ws;                       // 98304 B
  u64*   h_ex    = (u64*)(ws + 98304);               // 2*64*384*8 = 393216 B
  float* xproj   = (float*)(ws + 98304 + 393216);
  const size_t fixed = 98304 + 393216;

  // adaptive time-chunk so xproj fits in ws
  int Tc = 1024;
  while (Tc > 8 && fixed + (size_t)Tc * NBATCH * FH * 4 > ws_size) Tc >>= 1;

  const int revs[5] = {1, 0, 1, 0, 1};
  for (int l = 0; l < 5; ++l) {
    const float* xin = (l == 0) ? x : out;
    for (int t0 = 0; t0 < T_SEQ; t0 += Tc) {
      const int nyb = (Tc * NBATCH) / 128;
      gemm_xproj<<<dim3(nyb * 12), 256, 0, stream>>>(
          xin, Wi + (size_t)l * DD * FH,
          bs + (size_t)l * FH, xproj, t0, revs[l]);
      lstm_recur<<<192, RTHREADS, RSMEM_BYTES, stream>>>(
          xproj, Wh + (size_t)l * DD * FH, out, h_ex, c_state,
          t0, Tc, revs[l], l);
    }
  }
}